// Round 5
// baseline (143.963 us; speedup 1.0000x reference)
//
#include <hip/hip_runtime.h>
#include <math.h>

#define THREADS 256
#define NWAVE 4
#define QB 64            // queries per block (1 per lane)
#define TILE 1024        // targets per LDS tile (pair-packed)

typedef float v2f __attribute__((ext_vector_type(2)));

__device__ __forceinline__ v2f pk_mul(v2f a, v2f b) {
    v2f d;
    asm("v_pk_mul_f32 %0, %1, %2" : "=v"(d) : "v"(a), "v"(b));
    return d;
}
__device__ __forceinline__ v2f pk_fma(v2f a, v2f b, v2f c) {
    v2f d;
    asm("v_pk_fma_f32 %0, %1, %2, %3" : "=v"(d) : "v"(a), "v"(b), "v"(c));
    return d;
}

union F4 { float4 f4; v2f v[2]; };

// sorted insert of scalar C into L0<=..<=L4
#define INS5(L0,L1,L2,L3,L4,C) do { float m_=(C), n_;          \
    n_=fminf(L0,m_); m_=fmaxf(L0,m_); L0=n_;                   \
    n_=fminf(L1,m_); m_=fmaxf(L1,m_); L1=n_;                   \
    n_=fminf(L2,m_); m_=fmaxf(L2,m_); L2=n_;                   \
    n_=fminf(L3,m_); m_=fmaxf(L3,m_); L3=n_;                   \
    L4=fminf(L4,m_); } while (0)

// ---------------- Phase A: split scans -> partials in ws ----------------
// role 0: q=gt, t=pred (chamfer fwd)   role 1: q=pred, t=gt (chamfer bac)
// role 2: q=pred, t=pred (knn top-5, self dropped later as global min)
__global__ __launch_bounds__(THREADS) void scanA_kernel(
    const float* __restrict__ pred, const float* __restrict__ gt,
    float* __restrict__ chamPart, float* __restrict__ knnPart,
    int B, int N, int chunks, int tsK, int tsC, int knnBlocks)
{
    __shared__ float4 ptile[TILE];          // [2g]={x0,x1,y0,y1} [2g+1]={z0,z1,w0,w1}
    __shared__ float part[NWAVE][QB][10];

    const float FLT_INF = 3.4e38f;

    int role, b, chunk, split, segLen;
    if ((int)blockIdx.x < knnBlocks) {
        role = 2;
        int u = blockIdx.x;
        split = u % tsK; u /= tsK;
        chunk = u % chunks; b = u / chunks;
        segLen = (N + tsK - 1) / tsK;
    } else {
        int u = blockIdx.x - knnBlocks;
        int perRole = B * chunks * tsC;
        role = u / perRole; u %= perRole;
        split = u % tsC; u /= tsC;
        chunk = u % chunks; b = u / chunks;
        segLen = (N + tsC - 1) / tsC;
    }
    int tBegin = split * segLen;
    int tEnd = min(tBegin + segLen, N);

    int w = threadIdx.x >> 6, l = threadIdx.x & 63;
    int qi = chunk * QB + l;

    const float* qb = (((role == 0) ? gt : pred)) + (size_t)b * N * 3;
    const float* tb = (((role == 1) ? gt : pred)) + (size_t)b * N * 3;

    float qx = 0.f, qy = 0.f, qz = 0.f;
    if (qi < N) { qx = qb[qi*3]; qy = qb[qi*3+1]; qz = qb[qi*3+2]; }
    v2f Qxx = {qx, qx}, Qyy = {qy, qy}, Qzz = {qz, qz};
    v2f M2 = {-2.f, -2.f};

    float mA = FLT_INF, mB = FLT_INF, mC = FLT_INF, mD = FLT_INF;     // chamfer
    float e0=FLT_INF,e1=FLT_INF,e2=FLT_INF,e3=FLT_INF,e4=FLT_INF;    // knn even
    float o0=FLT_INF,o1=FLT_INF,o2=FLT_INF,o3=FLT_INF,o4=FLT_INF;    // knn odd

    for (int t0 = tBegin; t0 < tEnd; t0 += TILE) {
        int cnt = min(TILE, tEnd - t0);
        int groups = (cnt + 1) >> 1;
        for (int g = threadIdx.x; g < groups; g += THREADS) {
            int ta = t0 + 2*g;
            float x0 = tb[ta*3], y0 = tb[ta*3+1], z0 = tb[ta*3+2];
            float x1 = 1e18f, y1 = 0.f, z1 = 0.f;
            if (2*g + 1 < cnt) { x1 = tb[ta*3+3]; y1 = tb[ta*3+4]; z1 = tb[ta*3+5]; }
            float w0 = fmaf(x0,x0,fmaf(y0,y0,z0*z0));
            float w1 = fmaf(x1,x1,fmaf(y1,y1,z1*z1));
            ptile[2*g]   = make_float4(x0,x1,y0,y1);
            ptile[2*g+1] = make_float4(z0,z1,w0,w1);
        }
        __syncthreads();

        int gseg = (groups + NWAVE - 1) / NWAVE;
        int gb = w * gseg, ge = min(gb + gseg, groups);

        if (role < 2) {
            int g = gb;
            for (; g + 2 <= ge; g += 2) {
                F4 A0, B0, A1, B1;
                A0.f4 = ptile[2*g];   B0.f4 = ptile[2*g+1];
                A1.f4 = ptile[2*g+2]; B1.f4 = ptile[2*g+3];
                v2f d0 = pk_mul(Qzz, B0.v[0]);
                d0 = pk_fma(Qyy, A0.v[1], d0);
                d0 = pk_fma(Qxx, A0.v[0], d0);
                v2f c0 = pk_fma(d0, M2, B0.v[1]);
                v2f d1 = pk_mul(Qzz, B1.v[0]);
                d1 = pk_fma(Qyy, A1.v[1], d1);
                d1 = pk_fma(Qxx, A1.v[0], d1);
                v2f c1 = pk_fma(d1, M2, B1.v[1]);
                mA = fminf(mA, c0.x); mB = fminf(mB, c0.y);
                mC = fminf(mC, c1.x); mD = fminf(mD, c1.y);
            }
            for (; g < ge; ++g) {
                F4 A0, B0;
                A0.f4 = ptile[2*g]; B0.f4 = ptile[2*g+1];
                v2f d0 = pk_mul(Qzz, B0.v[0]);
                d0 = pk_fma(Qyy, A0.v[1], d0);
                d0 = pk_fma(Qxx, A0.v[0], d0);
                v2f c0 = pk_fma(d0, M2, B0.v[1]);
                mA = fminf(mA, c0.x); mB = fminf(mB, c0.y);
            }
        } else {
            for (int g = gb; g < ge; ++g) {
                F4 A0, B0;
                A0.f4 = ptile[2*g]; B0.f4 = ptile[2*g+1];
                v2f d0 = pk_mul(Qzz, B0.v[0]);
                d0 = pk_fma(Qyy, A0.v[1], d0);
                d0 = pk_fma(Qxx, A0.v[0], d0);
                v2f c0 = pk_fma(d0, M2, B0.v[1]);
                INS5(e0,e1,e2,e3,e4, c0.x);
                INS5(o0,o1,o2,o3,o4, c0.y);
            }
        }
        __syncthreads();
    }

    if (role < 2) {
        part[w][l][0] = fminf(fminf(mA, mB), fminf(mC, mD));
    } else {
        part[w][l][0]=e0; part[w][l][1]=e1; part[w][l][2]=e2; part[w][l][3]=e3; part[w][l][4]=e4;
        part[w][l][5]=o0; part[w][l][6]=o1; part[w][l][7]=o2; part[w][l][8]=o3; part[w][l][9]=o4;
    }
    __syncthreads();

    if (threadIdx.x < QB) {
        int t = threadIdx.x;
        int q = chunk * QB + t;
        if (q < N) {
            if (role < 2) {
                float m = fminf(fminf(part[0][t][0], part[1][t][0]),
                                fminf(part[2][t][0], part[3][t][0]));
                chamPart[(((size_t)role * B + b) * N + q) * tsC + split] = m;
            } else {
                float s0=FLT_INF,s1=FLT_INF,s2=FLT_INF,s3=FLT_INF,s4=FLT_INF;
                #pragma unroll
                for (int ww = 0; ww < NWAVE; ++ww)
                    #pragma unroll
                    for (int k = 0; k < 10; ++k)
                        INS5(s0,s1,s2,s3,s4, part[ww][t][k]);
                float* kp = &knnPart[(((size_t)b * N + q) * tsK + split) * 5];
                kp[0]=s0; kp[1]=s1; kp[2]=s2; kp[3]=s3; kp[4]=s4;
            }
        }
    }
}

// ---------------- Phase B: merge partials, compute losses ----------------
__global__ __launch_bounds__(THREADS) void mergeB_kernel(
    const float* __restrict__ pred, const float* __restrict__ gt,
    const float* __restrict__ radius,
    const float* __restrict__ chamPart, const float* __restrict__ knnPart,
    float* __restrict__ acc, int B, int N, int tsK, int tsC)
{
    const float FLT_INF = 3.4e38f;
    const float RADIUS = 0.07f;
    const float INV_H2 = 1.0f / (0.03f * 0.03f);
    const float EPSV = 1e-12f;

    __shared__ float redc[NWAVE], redu[NWAVE];

    int gid = blockIdx.x * THREADS + threadIdx.x;
    int BN = B * N;
    float cd = 0.f, uni = 0.f;

    if (gid < 2 * BN) {
        int role = gid / BN, q = gid % BN, b = q / N, qi = q % N;
        const float* qb = ((role == 0) ? gt : pred) + (size_t)b * N * 3;
        float qx = qb[qi*3], qy = qb[qi*3+1], qz = qb[qi*3+2];
        float na = fmaf(qx,qx,fmaf(qy,qy,qz*qz));
        const float* cp = &chamPart[(((size_t)role * B + b) * N + qi) * tsC];
        float m = cp[0];
        for (int s = 1; s < tsC; ++s) m = fminf(m, cp[s]);
        float wgt = (role == 0) ? 0.8f : 0.2f;
        cd = wgt * (na + m) / radius[b];
    } else if (gid < 3 * BN) {
        int q = gid - 2 * BN, b = q / N, qi = q % N;
        const float* qb = pred + (size_t)b * N * 3;
        float qx = qb[qi*3], qy = qb[qi*3+1], qz = qb[qi*3+2];
        float na = fmaf(qx,qx,fmaf(qy,qy,qz*qz));
        const float* kp = &knnPart[((size_t)b * N + qi) * tsK * 5];
        float s0=FLT_INF,s1=FLT_INF,s2=FLT_INF,s3=FLT_INF,s4=FLT_INF;
        for (int k = 0; k < tsK * 5; ++k) INS5(s0,s1,s2,s3,s4, kp[k]);
        // s0 = self (global min) dropped; ranks 1..4 are the 4-NN
        float ss[4] = {s1, s2, s3, s4};
        #pragma unroll
        for (int k = 0; k < 4; ++k) {
            float d2 = fmaxf(na + ss[k], EPSV);
            float dist = sqrtf(d2);
            float wgt = __expf(-d2 * INV_H2);
            uni += (RADIUS - dist) * wgt;
        }
    }

    int w = threadIdx.x >> 6, l = threadIdx.x & 63;
    #pragma unroll
    for (int off = 32; off > 0; off >>= 1) {
        cd  += __shfl_down(cd, off, 64);
        uni += __shfl_down(uni, off, 64);
    }
    if (l == 0) { redc[w] = cd; redu[w] = uni; }
    __syncthreads();
    if (threadIdx.x == 0) {
        atomicAdd(&acc[0], redc[0] + redc[1] + redc[2] + redc[3]);
        atomicAdd(&acc[1], redu[0] + redu[1] + redu[2] + redu[3]);
    }
}

// ---------------- Fallback: proven R3 monolithic kernel ----------------
__device__ __forceinline__ float sdist(float qx,float qy,float qz,float4 t) {
    return fmaf(-2.f, fmaf(qx,t.x,fmaf(qy,t.y,qz*t.z)), t.w);
}
__global__ __launch_bounds__(THREADS) void mono_kernel(
    const float* __restrict__ pred, const float* __restrict__ gt,
    const float* __restrict__ radius, float* __restrict__ acc,
    int B, int N, int chunksPerBatch)
{
    __shared__ float4 tgt[2048];
    __shared__ float part[NWAVE][128][5];
    __shared__ float naArr[128];
    __shared__ float red[NWAVE];
    const float FLT_INF = 3.4e38f;
    const float RADIUS = 0.07f;
    const float INV_H2 = 1.0f / (0.03f * 0.03f);
    const float EPSV = 1e-12f;

    int blocksPerRole = B * chunksPerBatch;
    int role  = blockIdx.x / blocksPerRole;
    int rem   = blockIdx.x % blocksPerRole;
    int b     = rem / chunksPerBatch;
    int chunk = rem % chunksPerBatch;
    int w = threadIdx.x >> 6, l = threadIdx.x & 63;
    int qi0 = chunk * 128 + l, qi1 = qi0 + 64;
    const float* qb = (((role == 0) ? gt : pred)) + (size_t)b * N * 3;
    const float* tb = (((role == 1) ? gt : pred)) + (size_t)b * N * 3;
    float q0x=0,q0y=0,q0z=0,q1x=0,q1y=0,q1z=0;
    if (qi0 < N) { q0x=qb[qi0*3]; q0y=qb[qi0*3+1]; q0z=qb[qi0*3+2]; }
    if (qi1 < N) { q1x=qb[qi1*3]; q1y=qb[qi1*3+1]; q1z=qb[qi1*3+2]; }
    float na0 = fmaf(q0x,q0x,fmaf(q0y,q0y,q0z*q0z));
    float na1 = fmaf(q1x,q1x,fmaf(q1y,q1y,q1z*q1z));
    if (w == 0) { naArr[l] = na0; naArr[l+64] = na1; }
    float mA=FLT_INF,mB=FLT_INF;
    float e0=FLT_INF,e1=FLT_INF,e2=FLT_INF,e3=FLT_INF,e4=FLT_INF;
    float o0=FLT_INF,o1=FLT_INF,o2=FLT_INF,o3=FLT_INF,o4=FLT_INF;
    for (int t0 = 0; t0 < N; t0 += 2048) {
        int cnt = min(2048, N - t0);
        for (int k = threadIdx.x; k < cnt; k += THREADS) {
            float x = tb[(size_t)(t0+k)*3], y = tb[(size_t)(t0+k)*3+1], z = tb[(size_t)(t0+k)*3+2];
            tgt[k] = make_float4(x,y,z,fmaf(x,x,fmaf(y,y,z*z)));
        }
        __syncthreads();
        int segsz = (cnt + NWAVE - 1)/NWAVE;
        int jb = w*segsz, je = min(jb+segsz, cnt);
        if (role < 2) {
            for (int j = jb; j < je; ++j) {
                float4 t = tgt[j];
                mA = fminf(mA, sdist(q0x,q0y,q0z,t));
                mB = fminf(mB, sdist(q1x,q1y,q1z,t));
            }
        } else {
            for (int j = jb; j < je; ++j) {
                float4 t = tgt[j];
                INS5(e0,e1,e2,e3,e4, sdist(q0x,q0y,q0z,t));
                INS5(o0,o1,o2,o3,o4, sdist(q1x,q1y,q1z,t));
            }
        }
        __syncthreads();
    }
    if (role < 2) { part[w][l][0]=mA; part[w][l+64][0]=mB; }
    else {
        part[w][l][0]=e0; part[w][l][1]=e1; part[w][l][2]=e2; part[w][l][3]=e3; part[w][l][4]=e4;
        part[w][l+64][0]=o0; part[w][l+64][1]=o1; part[w][l+64][2]=o2; part[w][l+64][3]=o3; part[w][l+64][4]=o4;
    }
    __syncthreads();
    float contrib = 0.f;
    int t = threadIdx.x;
    if (t < 128) {
        int q = chunk*128 + t;
        if (q < N) {
            float inv_r = 1.0f / radius[b];
            float na = naArr[t];
            if (role < 2) {
                float best = fminf(fminf(part[0][t][0],part[1][t][0]),
                                   fminf(part[2][t][0],part[3][t][0]));
                contrib = ((role==0)?0.8f:0.2f) * inv_r * (na + best);
            } else {
                float s0=FLT_INF,s1=FLT_INF,s2=FLT_INF,s3=FLT_INF,s4=FLT_INF;
                #pragma unroll
                for (int ww = 0; ww < NWAVE; ++ww)
                    #pragma unroll
                    for (int k = 0; k < 5; ++k)
                        INS5(s0,s1,s2,s3,s4, part[ww][t][k]);
                float ss[4] = {s1,s2,s3,s4};
                float s = 0.f;
                #pragma unroll
                for (int k = 0; k < 4; ++k) {
                    float d2 = fmaxf(na + ss[k], EPSV);
                    s += (RADIUS - sqrtf(d2)) * __expf(-d2 * INV_H2);
                }
                contrib = s;
            }
        }
    }
    #pragma unroll
    for (int off = 32; off > 0; off >>= 1) contrib += __shfl_down(contrib, off, 64);
    if (l == 0) red[w] = contrib;
    __syncthreads();
    if (threadIdx.x == 0)
        atomicAdd(&acc[role < 2 ? 0 : 1], red[0]+red[1]+red[2]+red[3]);
}

__global__ void upsample_final_kernel(const float* __restrict__ acc,
                                      float* __restrict__ out,
                                      float invCd, float invUni)
{
    out[0] = fmaf(acc[0], invCd, 0.1f * acc[1] * invUni);
}

extern "C" void kernel_launch(void* const* d_in, const int* in_sizes, int n_in,
                              void* d_out, int out_size, void* d_ws, size_t ws_size,
                              hipStream_t stream) {
    const float* pred   = (const float*)d_in[0];
    const float* gt     = (const float*)d_in[1];
    const float* radius = (const float*)d_in[2];
    float* out = (float*)d_out;
    float* acc = (float*)d_ws;

    int B = in_sizes[2];
    int N = in_sizes[0] / (3 * B);
    size_t BN = (size_t)B * N;

    hipMemsetAsync(acc, 0, 2 * sizeof(float), stream);

    int tsK = 4, tsC = 2;
    size_t chamBytes = 2 * BN * tsC * sizeof(float);
    size_t knnBytes  = BN * tsK * 5 * sizeof(float);
    size_t need = 64 + chamBytes + knnBytes;

    if (ws_size >= need) {
        float* chamPart = (float*)((char*)d_ws + 64);
        float* knnPart  = chamPart + 2 * BN * tsC;
        int chunks = (N + QB - 1) / QB;
        int knnBlocks  = B * chunks * tsK;
        int chamBlocks = 2 * B * chunks * tsC;
        scanA_kernel<<<knnBlocks + chamBlocks, THREADS, 0, stream>>>(
            pred, gt, chamPart, knnPart, B, N, chunks, tsK, tsC, knnBlocks);
        int mb = (int)((3 * BN + THREADS - 1) / THREADS);
        mergeB_kernel<<<mb, THREADS, 0, stream>>>(pred, gt, radius,
                                                  chamPart, knnPart, acc, B, N, tsK, tsC);
    } else {
        int chunksPerBatch = (N + 127) / 128;
        int blocks = 3 * B * chunksPerBatch;
        mono_kernel<<<blocks, THREADS, 0, stream>>>(pred, gt, radius, acc,
                                                    B, N, chunksPerBatch);
    }

    float invCd  = 1.0f / ((float)B * (float)N);
    float invUni = 1.0f / ((float)B * (float)N * 4.0f);
    upsample_final_kernel<<<1, 1, 0, stream>>>(acc, out, invCd, invUni);
}

// Round 6
// 134.349 us; speedup vs baseline: 1.0716x; 1.0716x over previous
//
#include <hip/hip_runtime.h>
#include <math.h>

#define THREADS 256
#define NWAVE 4
#define QB 64            // queries per block (1 per lane)
#define TILEG 512        // groups per LDS tile (2 targets/group -> 1024 targets)

typedef float v2f __attribute__((ext_vector_type(2)));

__device__ __forceinline__ v2f pk_mul(v2f a, v2f b) {
    v2f d;
    asm("v_pk_mul_f32 %0, %1, %2" : "=v"(d) : "v"(a), "v"(b));
    return d;
}
__device__ __forceinline__ v2f pk_fma(v2f a, v2f b, v2f c) {
    v2f d;
    asm("v_pk_fma_f32 %0, %1, %2, %3" : "=v"(d) : "v"(a), "v"(b), "v"(c));
    return d;
}

union F4 { float4 f4; v2f v[2]; };

#define MED3 __builtin_amdgcn_fmed3f

// med3 sorted insert: 5 independent ops, no dependency chain.
// L0<=L1<=..<=L4 -> five smallest of {L*, C}
#define INS5(L0,L1,L2,L3,L4,C) do { float c_=(C);              \
    float n0_=fminf(L0,c_);                                    \
    float n1_=MED3(L0,L1,c_);                                  \
    float n2_=MED3(L1,L2,c_);                                  \
    float n3_=MED3(L2,L3,c_);                                  \
    float n4_=MED3(L3,L4,c_);                                  \
    L0=n0_; L1=n1_; L2=n2_; L3=n3_; L4=n4_; } while (0)

// ---------------- Phase A: persistent balanced scan -> partials in ws ----------------
// items [0, knnItems): role 2 knn (targets split tsK ways)
// items [knnItems, total): roles 0/1 chamfer (targets split tsC ways)
__global__ __launch_bounds__(THREADS) void scanA_kernel(
    const float* __restrict__ pred, const float* __restrict__ gt,
    float* __restrict__ chamPart, float* __restrict__ knnPart,
    int B, int N, int chunks, int tsK, int tsC, int knnItems, int totalItems)
{
    __shared__ float4 tA[TILEG];          // {x0,x1,y0,y1}
    __shared__ float4 tB[TILEG];          // {z0,z1,w0,w1}
    __shared__ float part[NWAVE][QB][10];

    const float FLT_INF = 3.4e38f;
    int w = threadIdx.x >> 6, l = threadIdx.x & 63;

    for (int item = blockIdx.x; item < totalItems; item += gridDim.x) {
        int role, b, chunk, split, segLen;
        if (item < knnItems) {
            role = 2;
            int u = item;
            split = u % tsK; u /= tsK;
            chunk = u % chunks; b = u / chunks;
            segLen = (N + tsK - 1) / tsK;
        } else {
            int u = item - knnItems;
            int perRole = B * chunks * tsC;
            role = u / perRole; u %= perRole;
            split = u % tsC; u /= tsC;
            chunk = u % chunks; b = u / chunks;
            segLen = (N + tsC - 1) / tsC;
        }
        int tBegin = split * segLen;
        int tEnd = min(tBegin + segLen, N);

        int qi = chunk * QB + l;
        const float* qb = (((role == 0) ? gt : pred)) + (size_t)b * N * 3;
        const float* tb = (((role == 1) ? gt : pred)) + (size_t)b * N * 3;

        float qx = 0.f, qy = 0.f, qz = 0.f;
        if (qi < N) { qx = qb[qi*3]; qy = qb[qi*3+1]; qz = qb[qi*3+2]; }
        v2f Qxx = {qx, qx}, Qyy = {qy, qy}, Qzz = {qz, qz};
        v2f M2 = {-2.f, -2.f};

        float mA = FLT_INF, mB = FLT_INF, mC = FLT_INF, mD = FLT_INF;    // chamfer
        float e0=FLT_INF,e1=FLT_INF,e2=FLT_INF,e3=FLT_INF,e4=FLT_INF;    // knn even
        float o0=FLT_INF,o1=FLT_INF,o2=FLT_INF,o3=FLT_INF,o4=FLT_INF;    // knn odd

        for (int t0 = t0 = tBegin; t0 < tEnd; t0 += 2 * TILEG) {
            int cnt = min(2 * TILEG, tEnd - t0);          // targets this tile
            int gcnt = (cnt + 1) >> 1;                    // groups this tile

            // stage 4 targets (2 groups) per thread; fast path: aligned dwordx4 x3
            int t4 = threadIdx.x;                         // group pair index
            int base = 4 * t4;                            // first target (rel)
            if (base + 4 <= cnt) {
                const float4* src = reinterpret_cast<const float4*>(tb + (size_t)(t0 + base) * 3);
                float4 L0 = src[0], L1 = src[1], L2 = src[2];
                float x0=L0.x, y0=L0.y, z0=L0.z,  x1=L0.w, y1=L1.x, z1=L1.y;
                float x2=L1.z, y2=L1.w, z2=L2.x,  x3=L2.y, y3=L2.z, z3=L2.w;
                float w0=fmaf(x0,x0,fmaf(y0,y0,z0*z0));
                float w1=fmaf(x1,x1,fmaf(y1,y1,z1*z1));
                float w2=fmaf(x2,x2,fmaf(y2,y2,z2*z2));
                float w3=fmaf(x3,x3,fmaf(y3,y3,z3*z3));
                tA[2*t4]   = make_float4(x0,x1,y0,y1);
                tB[2*t4]   = make_float4(z0,z1,w0,w1);
                tA[2*t4+1] = make_float4(x2,x3,y2,y3);
                tB[2*t4+1] = make_float4(z2,z3,w2,w3);
            } else if (base < cnt) {
                // tail: scalar staging with padding
                for (int g = base / 2; g < gcnt && g < base / 2 + 2; ++g) {
                    int ta = t0 + 2 * g;
                    float x0 = tb[ta*3], y0 = tb[ta*3+1], z0 = tb[ta*3+2];
                    float x1 = 1e18f, y1 = 0.f, z1 = 0.f;
                    if (2*g + 1 < cnt) { x1 = tb[ta*3+3]; y1 = tb[ta*3+4]; z1 = tb[ta*3+5]; }
                    float w0=fmaf(x0,x0,fmaf(y0,y0,z0*z0));
                    float w1=fmaf(x1,x1,fmaf(y1,y1,z1*z1));
                    tA[g] = make_float4(x0,x1,y0,y1);
                    tB[g] = make_float4(z0,z1,w0,w1);
                }
            }
            __syncthreads();

            int gseg = (gcnt + NWAVE - 1) / NWAVE;
            int gb = w * gseg, ge = min(gb + gseg, gcnt);

            if (role < 2) {
                int g = gb;
                for (; g + 2 <= ge; g += 2) {
                    F4 a0, b0, a1, b1;
                    a0.f4 = tA[g];   b0.f4 = tB[g];
                    a1.f4 = tA[g+1]; b1.f4 = tB[g+1];
                    v2f d0 = pk_mul(Qzz, b0.v[0]);
                    d0 = pk_fma(Qyy, a0.v[1], d0);
                    d0 = pk_fma(Qxx, a0.v[0], d0);
                    v2f c0 = pk_fma(d0, M2, b0.v[1]);
                    v2f d1 = pk_mul(Qzz, b1.v[0]);
                    d1 = pk_fma(Qyy, a1.v[1], d1);
                    d1 = pk_fma(Qxx, a1.v[0], d1);
                    v2f c1 = pk_fma(d1, M2, b1.v[1]);
                    mA = fminf(mA, c0.x); mB = fminf(mB, c0.y);
                    mC = fminf(mC, c1.x); mD = fminf(mD, c1.y);
                }
                for (; g < ge; ++g) {
                    F4 a0, b0;
                    a0.f4 = tA[g]; b0.f4 = tB[g];
                    v2f d0 = pk_mul(Qzz, b0.v[0]);
                    d0 = pk_fma(Qyy, a0.v[1], d0);
                    d0 = pk_fma(Qxx, a0.v[0], d0);
                    v2f c0 = pk_fma(d0, M2, b0.v[1]);
                    mA = fminf(mA, c0.x); mB = fminf(mB, c0.y);
                }
            } else {
                for (int g = gb; g < ge; ++g) {
                    F4 a0, b0;
                    a0.f4 = tA[g]; b0.f4 = tB[g];
                    v2f d0 = pk_mul(Qzz, b0.v[0]);
                    d0 = pk_fma(Qyy, a0.v[1], d0);
                    d0 = pk_fma(Qxx, a0.v[0], d0);
                    v2f c0 = pk_fma(d0, M2, b0.v[1]);
                    INS5(e0,e1,e2,e3,e4, c0.x);
                    INS5(o0,o1,o2,o3,o4, c0.y);
                }
            }
            __syncthreads();
        }

        if (role < 2) {
            part[w][l][0] = fminf(fminf(mA, mB), fminf(mC, mD));
        } else {
            part[w][l][0]=e0; part[w][l][1]=e1; part[w][l][2]=e2; part[w][l][3]=e3; part[w][l][4]=e4;
            part[w][l][5]=o0; part[w][l][6]=o1; part[w][l][7]=o2; part[w][l][8]=o3; part[w][l][9]=o4;
        }
        __syncthreads();

        if (threadIdx.x < QB) {
            int t = threadIdx.x;
            int q = chunk * QB + t;
            if (q < N) {
                if (role < 2) {
                    float m = fminf(fminf(part[0][t][0], part[1][t][0]),
                                    fminf(part[2][t][0], part[3][t][0]));
                    chamPart[(((size_t)role * B + b) * N + q) * tsC + split] = m;
                } else {
                    float s0=FLT_INF,s1=FLT_INF,s2=FLT_INF,s3=FLT_INF,s4=FLT_INF;
                    #pragma unroll
                    for (int ww = 0; ww < NWAVE; ++ww)
                        #pragma unroll
                        for (int k = 0; k < 10; ++k)
                            INS5(s0,s1,s2,s3,s4, part[ww][t][k]);
                    float* kp = &knnPart[(((size_t)b * N + q) * tsK + split) * 5];
                    kp[0]=s0; kp[1]=s1; kp[2]=s2; kp[3]=s3; kp[4]=s4;
                }
            }
        }
        __syncthreads();   // LDS reuse across items
    }
}

// ---------------- Phase B: merge partials, compute losses ----------------
__global__ __launch_bounds__(THREADS) void mergeB_kernel(
    const float* __restrict__ pred, const float* __restrict__ gt,
    const float* __restrict__ radius,
    const float* __restrict__ chamPart, const float* __restrict__ knnPart,
    float* __restrict__ acc, int B, int N, int tsK, int tsC)
{
    const float FLT_INF = 3.4e38f;
    const float RADIUS = 0.07f;
    const float INV_H2 = 1.0f / (0.03f * 0.03f);
    const float EPSV = 1e-12f;

    __shared__ float redc[NWAVE], redu[NWAVE];

    int gid = blockIdx.x * THREADS + threadIdx.x;
    int BN = B * N;
    float cd = 0.f, uni = 0.f;

    if (gid < 2 * BN) {
        int role = gid / BN, q = gid % BN, b = q / N, qi = q % N;
        const float* qb = ((role == 0) ? gt : pred) + (size_t)b * N * 3;
        float qx = qb[qi*3], qy = qb[qi*3+1], qz = qb[qi*3+2];
        float na = fmaf(qx,qx,fmaf(qy,qy,qz*qz));
        const float* cp = &chamPart[(((size_t)role * B + b) * N + qi) * tsC];
        float m = cp[0];
        for (int s = 1; s < tsC; ++s) m = fminf(m, cp[s]);
        float wgt = (role == 0) ? 0.8f : 0.2f;
        cd = wgt * (na + m) / radius[b];
    } else if (gid < 3 * BN) {
        int q = gid - 2 * BN, b = q / N, qi = q % N;
        const float* qb = pred + (size_t)b * N * 3;
        float qx = qb[qi*3], qy = qb[qi*3+1], qz = qb[qi*3+2];
        float na = fmaf(qx,qx,fmaf(qy,qy,qz*qz));
        const float* kp = &knnPart[((size_t)b * N + qi) * tsK * 5];
        float s0=FLT_INF,s1=FLT_INF,s2=FLT_INF,s3=FLT_INF,s4=FLT_INF;
        for (int k = 0; k < tsK * 5; ++k) INS5(s0,s1,s2,s3,s4, kp[k]);
        // s0 = self (global min) dropped; ranks 1..4 are the 4-NN
        float ss[4] = {s1, s2, s3, s4};
        #pragma unroll
        for (int k = 0; k < 4; ++k) {
            float d2 = fmaxf(na + ss[k], EPSV);
            float dist = sqrtf(d2);
            float wgt = __expf(-d2 * INV_H2);
            uni += (RADIUS - dist) * wgt;
        }
    }

    int w = threadIdx.x >> 6, l = threadIdx.x & 63;
    #pragma unroll
    for (int off = 32; off > 0; off >>= 1) {
        cd  += __shfl_down(cd, off, 64);
        uni += __shfl_down(uni, off, 64);
    }
    if (l == 0) { redc[w] = cd; redu[w] = uni; }
    __syncthreads();
    if (threadIdx.x == 0) {
        atomicAdd(&acc[0], redc[0] + redc[1] + redc[2] + redc[3]);
        atomicAdd(&acc[1], redu[0] + redu[1] + redu[2] + redu[3]);
    }
}

// ---------------- Fallback: proven monolithic kernel (small ws) ----------------
__device__ __forceinline__ float sdist(float qx,float qy,float qz,float4 t) {
    return fmaf(-2.f, fmaf(qx,t.x,fmaf(qy,t.y,qz*t.z)), t.w);
}
__global__ __launch_bounds__(THREADS) void mono_kernel(
    const float* __restrict__ pred, const float* __restrict__ gt,
    const float* __restrict__ radius, float* __restrict__ acc,
    int B, int N, int chunksPerBatch)
{
    __shared__ float4 tgt[2048];
    __shared__ float part[NWAVE][128][5];
    __shared__ float naArr[128];
    __shared__ float red[NWAVE];
    const float FLT_INF = 3.4e38f;
    const float RADIUS = 0.07f;
    const float INV_H2 = 1.0f / (0.03f * 0.03f);
    const float EPSV = 1e-12f;

    int blocksPerRole = B * chunksPerBatch;
    int role  = blockIdx.x / blocksPerRole;
    int rem   = blockIdx.x % blocksPerRole;
    int b     = rem / chunksPerBatch;
    int chunk = rem % chunksPerBatch;
    int w = threadIdx.x >> 6, l = threadIdx.x & 63;
    int qi0 = chunk * 128 + l, qi1 = qi0 + 64;
    const float* qb = (((role == 0) ? gt : pred)) + (size_t)b * N * 3;
    const float* tb = (((role == 1) ? gt : pred)) + (size_t)b * N * 3;
    float q0x=0,q0y=0,q0z=0,q1x=0,q1y=0,q1z=0;
    if (qi0 < N) { q0x=qb[qi0*3]; q0y=qb[qi0*3+1]; q0z=qb[qi0*3+2]; }
    if (qi1 < N) { q1x=qb[qi1*3]; q1y=qb[qi1*3+1]; q1z=qb[qi1*3+2]; }
    float na0 = fmaf(q0x,q0x,fmaf(q0y,q0y,q0z*q0z));
    float na1 = fmaf(q1x,q1x,fmaf(q1y,q1y,q1z*q1z));
    if (w == 0) { naArr[l] = na0; naArr[l+64] = na1; }
    float mA=FLT_INF,mB=FLT_INF;
    float e0=FLT_INF,e1=FLT_INF,e2=FLT_INF,e3=FLT_INF,e4=FLT_INF;
    float o0=FLT_INF,o1=FLT_INF,o2=FLT_INF,o3=FLT_INF,o4=FLT_INF;
    for (int t0 = 0; t0 < N; t0 += 2048) {
        int cnt = min(2048, N - t0);
        for (int k = threadIdx.x; k < cnt; k += THREADS) {
            float x = tb[(size_t)(t0+k)*3], y = tb[(size_t)(t0+k)*3+1], z = tb[(size_t)(t0+k)*3+2];
            tgt[k] = make_float4(x,y,z,fmaf(x,x,fmaf(y,y,z*z)));
        }
        __syncthreads();
        int segsz = (cnt + NWAVE - 1)/NWAVE;
        int jb = w*segsz, je = min(jb+segsz, cnt);
        if (role < 2) {
            for (int j = jb; j < je; ++j) {
                float4 t = tgt[j];
                mA = fminf(mA, sdist(q0x,q0y,q0z,t));
                mB = fminf(mB, sdist(q1x,q1y,q1z,t));
            }
        } else {
            for (int j = jb; j < je; ++j) {
                float4 t = tgt[j];
                INS5(e0,e1,e2,e3,e4, sdist(q0x,q0y,q0z,t));
                INS5(o0,o1,o2,o3,o4, sdist(q1x,q1y,q1z,t));
            }
        }
        __syncthreads();
    }
    if (role < 2) { part[w][l][0]=mA; part[w][l+64][0]=mB; }
    else {
        part[w][l][0]=e0; part[w][l][1]=e1; part[w][l][2]=e2; part[w][l][3]=e3; part[w][l][4]=e4;
        part[w][l+64][0]=o0; part[w][l+64][1]=o1; part[w][l+64][2]=o2; part[w][l+64][3]=o3; part[w][l+64][4]=o4;
    }
    __syncthreads();
    float contrib = 0.f;
    int t = threadIdx.x;
    if (t < 128) {
        int q = chunk*128 + t;
        if (q < N) {
            float inv_r = 1.0f / radius[b];
            float na = naArr[t];
            if (role < 2) {
                float best = fminf(fminf(part[0][t][0],part[1][t][0]),
                                   fminf(part[2][t][0],part[3][t][0]));
                contrib = ((role==0)?0.8f:0.2f) * inv_r * (na + best);
            } else {
                float s0=FLT_INF,s1=FLT_INF,s2=FLT_INF,s3=FLT_INF,s4=FLT_INF;
                #pragma unroll
                for (int ww = 0; ww < NWAVE; ++ww)
                    #pragma unroll
                    for (int k = 0; k < 5; ++k)
                        INS5(s0,s1,s2,s3,s4, part[ww][t][k]);
                float ss[4] = {s1,s2,s3,s4};
                float s = 0.f;
                #pragma unroll
                for (int k = 0; k < 4; ++k) {
                    float d2 = fmaxf(na + ss[k], EPSV);
                    s += (RADIUS - sqrtf(d2)) * __expf(-d2 * INV_H2);
                }
                contrib = s;
            }
        }
    }
    #pragma unroll
    for (int off = 32; off > 0; off >>= 1) contrib += __shfl_down(contrib, off, 64);
    if (l == 0) red[w] = contrib;
    __syncthreads();
    if (threadIdx.x == 0)
        atomicAdd(&acc[role < 2 ? 0 : 1], red[0]+red[1]+red[2]+red[3]);
}

__global__ void upsample_final_kernel(const float* __restrict__ acc,
                                      float* __restrict__ out,
                                      float invCd, float invUni)
{
    out[0] = fmaf(acc[0], invCd, 0.1f * acc[1] * invUni);
}

extern "C" void kernel_launch(void* const* d_in, const int* in_sizes, int n_in,
                              void* d_out, int out_size, void* d_ws, size_t ws_size,
                              hipStream_t stream) {
    const float* pred   = (const float*)d_in[0];
    const float* gt     = (const float*)d_in[1];
    const float* radius = (const float*)d_in[2];
    float* out = (float*)d_out;
    float* acc = (float*)d_ws;

    int B = in_sizes[2];
    int N = in_sizes[0] / (3 * B);
    size_t BN = (size_t)B * N;

    hipMemsetAsync(acc, 0, 2 * sizeof(float), stream);

    int tsK = 4, tsC = 2;
    size_t chamBytes = 2 * BN * tsC * sizeof(float);
    size_t knnBytes  = BN * tsK * 5 * sizeof(float);
    size_t need = 64 + chamBytes + knnBytes;

    if (ws_size >= need) {
        float* chamPart = (float*)((char*)d_ws + 64);
        float* knnPart  = chamPart + 2 * BN * tsC;
        int chunks = (N + QB - 1) / QB;
        int knnItems  = B * chunks * tsK;
        int chamItems = 2 * B * chunks * tsC;
        int totalItems = knnItems + chamItems;
        int grid = min(totalItems, 1024);
        scanA_kernel<<<grid, THREADS, 0, stream>>>(
            pred, gt, chamPart, knnPart, B, N, chunks, tsK, tsC, knnItems, totalItems);
        int mb = (int)((3 * BN + THREADS - 1) / THREADS);
        mergeB_kernel<<<mb, THREADS, 0, stream>>>(pred, gt, radius,
                                                  chamPart, knnPart, acc, B, N, tsK, tsC);
    } else {
        int chunksPerBatch = (N + 127) / 128;
        int blocks = 3 * B * chunksPerBatch;
        mono_kernel<<<blocks, THREADS, 0, stream>>>(pred, gt, radius, acc,
                                                    B, N, chunksPerBatch);
    }

    float invCd  = 1.0f / ((float)B * (float)N);
    float invUni = 1.0f / ((float)B * (float)N * 4.0f);
    upsample_final_kernel<<<1, 1, 0, stream>>>(acc, out, invCd, invUni);
}

// Round 7
// 94.542 us; speedup vs baseline: 1.5227x; 1.4211x over previous
//
#include <hip/hip_runtime.h>
#include <math.h>

#define THREADS 256
#define NWAVE 4
#define QB 64            // queries per block (1 per lane)
#define TILE 1024        // targets staged in LDS per tile (16 KB)
#define KSPLIT 2         // knn target split factor

#define MED3 __builtin_amdgcn_fmed3f

// branchless sorted insert via med3: 5 independent ops, no serial chain.
// Pre: L0<=L1<=L2<=L3<=L4. Post: five smallest of {L0..L4, C}, sorted.
#define INS5(L0,L1,L2,L3,L4,C) do { float c_=(C);              \
    float n0_=fminf(L0,c_);                                    \
    float n1_=MED3(L0,L1,c_);                                  \
    float n2_=MED3(L1,L2,c_);                                  \
    float n3_=MED3(L2,L3,c_);                                  \
    float n4_=MED3(L3,L4,c_);                                  \
    L0=n0_; L1=n1_; L2=n2_; L3=n3_; L4=n4_; } while (0)

__device__ __forceinline__ float sdist(float qx,float qy,float qz,float4 t) {
    return fmaf(-2.f, fmaf(qx,t.x,fmaf(qy,t.y,qz*t.z)), t.w);   // nb - 2*dot
}

// blocks [0, knnItems): role 2 (knn), targets split KSPLIT ways -> knnPart
// blocks [knnItems, ...): roles 0/1 (chamfer), full target scan -> atomic acc[0]
__global__ __launch_bounds__(THREADS) void scan_kernel(
    const float* __restrict__ pred, const float* __restrict__ gt,
    const float* __restrict__ radius, float* __restrict__ acc,
    float* __restrict__ knnPart, int B, int N, int chunks, int knnItems)
{
    __shared__ float4 tile[TILE];
    __shared__ float part[NWAVE][QB][5];
    __shared__ float red[NWAVE];

    const float FLT_INF = 3.4e38f;

    int w = threadIdx.x >> 6, l = threadIdx.x & 63;

    int role, b, chunk, split = 0, tBegin, tEnd;
    if ((int)blockIdx.x < knnItems) {
        role = 2;
        int u = blockIdx.x;
        split = u % KSPLIT; u /= KSPLIT;
        chunk = u % chunks; b = u / chunks;
        int seg = (N + KSPLIT - 1) / KSPLIT;
        tBegin = split * seg; tEnd = min(tBegin + seg, N);
    } else {
        int u = blockIdx.x - knnItems;
        int perRole = B * chunks;
        role = u / perRole; u %= perRole;
        chunk = u % chunks; b = u / chunks;
        tBegin = 0; tEnd = N;
    }

    int qi = chunk * QB + l;
    const float* qb = (((role == 0) ? gt : pred)) + (size_t)b * N * 3;
    const float* tb = (((role == 1) ? gt : pred)) + (size_t)b * N * 3;

    float qx = 0.f, qy = 0.f, qz = 0.f;
    if (qi < N) { qx = qb[qi*3]; qy = qb[qi*3+1]; qz = qb[qi*3+2]; }
    float na = fmaf(qx, qx, fmaf(qy, qy, qz * qz));

    float m0 = FLT_INF, m1 = FLT_INF, m2 = FLT_INF, m3 = FLT_INF;   // chamfer
    float b0 = FLT_INF, b1 = FLT_INF, b2 = FLT_INF, b3 = FLT_INF, b4 = FLT_INF; // knn

    for (int t0 = tBegin; t0 < tEnd; t0 += TILE) {
        int cnt = min(TILE, tEnd - t0);
        for (int k = threadIdx.x; k < cnt; k += THREADS) {
            float x = tb[(size_t)(t0 + k) * 3 + 0];
            float y = tb[(size_t)(t0 + k) * 3 + 1];
            float z = tb[(size_t)(t0 + k) * 3 + 2];
            tile[k] = make_float4(x, y, z, fmaf(x, x, fmaf(y, y, z * z)));
        }
        __syncthreads();

        int seg = (cnt + NWAVE - 1) / NWAVE;
        int jb = w * seg, je = min(jb + seg, cnt);

        if (role < 2) {
            int j = jb;
            for (; j + 4 <= je; j += 4) {
                float4 t0v = tile[j], t1v = tile[j+1], t2v = tile[j+2], t3v = tile[j+3];
                m0 = fminf(m0, sdist(qx,qy,qz,t0v));
                m1 = fminf(m1, sdist(qx,qy,qz,t1v));
                m2 = fminf(m2, sdist(qx,qy,qz,t2v));
                m3 = fminf(m3, sdist(qx,qy,qz,t3v));
            }
            for (; j < je; ++j) m0 = fminf(m0, sdist(qx,qy,qz,tile[j]));
        } else {
            int j = jb;
            for (; j + 2 <= je; j += 2) {
                float4 t0v = tile[j], t1v = tile[j+1];
                float c0 = sdist(qx,qy,qz,t0v);
                float c1 = sdist(qx,qy,qz,t1v);
                INS5(b0,b1,b2,b3,b4, c0);
                INS5(b0,b1,b2,b3,b4, c1);
            }
            for (; j < je; ++j) INS5(b0,b1,b2,b3,b4, sdist(qx,qy,qz,tile[j]));
        }
        __syncthreads();
    }

    if (role < 2) {
        part[w][l][0] = fminf(fminf(m0, m1), fminf(m2, m3));
    } else {
        part[w][l][0]=b0; part[w][l][1]=b1; part[w][l][2]=b2;
        part[w][l][3]=b3; part[w][l][4]=b4;
    }
    __syncthreads();

    if (role < 2) {
        // chamfer: finish per-query min, contribute to acc[0]
        float contrib = 0.f;
        if (threadIdx.x < QB) {
            int t = threadIdx.x;
            int q = chunk * QB + t;
            if (q < N) {
                // na of query t: recompute from its own loads is per-thread;
                // use part-free path: thread t == lane t of wave 0 held na only for its own qi.
                // Instead recompute na from global (cheap, L1-hot).
                const float* qp = qb + (size_t)(chunk * QB + t) * 3 - (size_t)(qi - qi) ; // silence
                float x = qb[q*3], y = qb[q*3+1], z = qb[q*3+2];
                float nq = fmaf(x,x,fmaf(y,y,z*z));
                float best = fminf(fminf(part[0][t][0], part[1][t][0]),
                                   fminf(part[2][t][0], part[3][t][0]));
                float wgt = (role == 0) ? 0.8f : 0.2f;
                contrib = wgt * (nq + best) / radius[b];
            }
        }
        #pragma unroll
        for (int off = 32; off > 0; off >>= 1) contrib += __shfl_down(contrib, off, 64);
        if (l == 0) red[w] = contrib;
        __syncthreads();
        if (threadIdx.x == 0) atomicAdd(&acc[0], red[0]+red[1]+red[2]+red[3]);
    } else {
        // knn: merge 4 waves' top-5 -> per-(query,split) top-5 partial in ws
        if (threadIdx.x < QB) {
            int t = threadIdx.x;
            int q = chunk * QB + t;
            if (q < N) {
                float s0=FLT_INF,s1=FLT_INF,s2=FLT_INF,s3=FLT_INF,s4=FLT_INF;
                #pragma unroll
                for (int ww = 0; ww < NWAVE; ++ww)
                    #pragma unroll
                    for (int k = 0; k < 5; ++k)
                        INS5(s0,s1,s2,s3,s4, part[ww][t][k]);
                float* kp = &knnPart[(((size_t)b * N + q) * KSPLIT + split) * 5];
                kp[0]=s0; kp[1]=s1; kp[2]=s2; kp[3]=s3; kp[4]=s4;
            }
        }
    }
}

// merge knn partials -> uniform loss into acc[1]
__global__ __launch_bounds__(THREADS) void mergeB_kernel(
    const float* __restrict__ pred, const float* __restrict__ knnPart,
    float* __restrict__ acc, int B, int N)
{
    const float FLT_INF = 3.4e38f;
    const float RADIUS = 0.07f;
    const float INV_H2 = 1.0f / (0.03f * 0.03f);
    const float EPSV = 1e-12f;

    __shared__ float redu[NWAVE];

    int gid = blockIdx.x * THREADS + threadIdx.x;
    int BN = B * N;
    float uni = 0.f;

    if (gid < BN) {
        int b = gid / N, qi = gid % N;
        const float* qp = pred + (size_t)b * N * 3 + (size_t)qi * 3;
        float x = qp[0], y = qp[1], z = qp[2];
        float na = fmaf(x,x,fmaf(y,y,z*z));
        const float* kp = &knnPart[(size_t)gid * KSPLIT * 5];
        float s0=FLT_INF,s1=FLT_INF,s2=FLT_INF,s3=FLT_INF,s4=FLT_INF;
        #pragma unroll
        for (int k = 0; k < KSPLIT * 5; ++k) INS5(s0,s1,s2,s3,s4, kp[k]);
        // s0 == self (exact global min, d2=0): dropped. ranks 1..4 = 4-NN.
        float ss[4] = {s1, s2, s3, s4};
        #pragma unroll
        for (int k = 0; k < 4; ++k) {
            float d2 = fmaxf(na + ss[k], EPSV);
            uni += (RADIUS - sqrtf(d2)) * __expf(-d2 * INV_H2);
        }
    }

    int w = threadIdx.x >> 6, l = threadIdx.x & 63;
    #pragma unroll
    for (int off = 32; off > 0; off >>= 1) uni += __shfl_down(uni, off, 64);
    if (l == 0) redu[w] = uni;
    __syncthreads();
    if (threadIdx.x == 0)
        atomicAdd(&acc[1], redu[0]+redu[1]+redu[2]+redu[3]);
}

// ---------------- Fallback: proven monolithic kernel (small ws) ----------------
__global__ __launch_bounds__(THREADS) void mono_kernel(
    const float* __restrict__ pred, const float* __restrict__ gt,
    const float* __restrict__ radius, float* __restrict__ acc,
    int B, int N, int chunksPerBatch)
{
    __shared__ float4 tgt[2048];
    __shared__ float part[NWAVE][128][5];
    __shared__ float naArr[128];
    __shared__ float red[NWAVE];
    const float FLT_INF = 3.4e38f;
    const float RADIUS = 0.07f;
    const float INV_H2 = 1.0f / (0.03f * 0.03f);
    const float EPSV = 1e-12f;

    int blocksPerRole = B * chunksPerBatch;
    int role  = blockIdx.x / blocksPerRole;
    int rem   = blockIdx.x % blocksPerRole;
    int b     = rem / chunksPerBatch;
    int chunk = rem % chunksPerBatch;
    int w = threadIdx.x >> 6, l = threadIdx.x & 63;
    int qi0 = chunk * 128 + l, qi1 = qi0 + 64;
    const float* qb = (((role == 0) ? gt : pred)) + (size_t)b * N * 3;
    const float* tb = (((role == 1) ? gt : pred)) + (size_t)b * N * 3;
    float q0x=0,q0y=0,q0z=0,q1x=0,q1y=0,q1z=0;
    if (qi0 < N) { q0x=qb[qi0*3]; q0y=qb[qi0*3+1]; q0z=qb[qi0*3+2]; }
    if (qi1 < N) { q1x=qb[qi1*3]; q1y=qb[qi1*3+1]; q1z=qb[qi1*3+2]; }
    float na0 = fmaf(q0x,q0x,fmaf(q0y,q0y,q0z*q0z));
    float na1 = fmaf(q1x,q1x,fmaf(q1y,q1y,q1z*q1z));
    if (w == 0) { naArr[l] = na0; naArr[l+64] = na1; }
    float mA=FLT_INF,mB=FLT_INF;
    float e0=FLT_INF,e1=FLT_INF,e2=FLT_INF,e3=FLT_INF,e4=FLT_INF;
    float o0=FLT_INF,o1=FLT_INF,o2=FLT_INF,o3=FLT_INF,o4=FLT_INF;
    for (int t0 = 0; t0 < N; t0 += 2048) {
        int cnt = min(2048, N - t0);
        for (int k = threadIdx.x; k < cnt; k += THREADS) {
            float x = tb[(size_t)(t0+k)*3], y = tb[(size_t)(t0+k)*3+1], z = tb[(size_t)(t0+k)*3+2];
            tgt[k] = make_float4(x,y,z,fmaf(x,x,fmaf(y,y,z*z)));
        }
        __syncthreads();
        int segsz = (cnt + NWAVE - 1)/NWAVE;
        int jb = w*segsz, je = min(jb+segsz, cnt);
        if (role < 2) {
            for (int j = jb; j < je; ++j) {
                float4 t = tgt[j];
                mA = fminf(mA, sdist(q0x,q0y,q0z,t));
                mB = fminf(mB, sdist(q1x,q1y,q1z,t));
            }
        } else {
            for (int j = jb; j < je; ++j) {
                float4 t = tgt[j];
                INS5(e0,e1,e2,e3,e4, sdist(q0x,q0y,q0z,t));
                INS5(o0,o1,o2,o3,o4, sdist(q1x,q1y,q1z,t));
            }
        }
        __syncthreads();
    }
    if (role < 2) { part[w][l][0]=mA; part[w][l+64][0]=mB; }
    else {
        part[w][l][0]=e0; part[w][l][1]=e1; part[w][l][2]=e2; part[w][l][3]=e3; part[w][l][4]=e4;
        part[w][l+64][0]=o0; part[w][l+64][1]=o1; part[w][l+64][2]=o2; part[w][l+64][3]=o3; part[w][l+64][4]=o4;
    }
    __syncthreads();
    float contrib = 0.f;
    int t = threadIdx.x;
    if (t < 128) {
        int q = chunk*128 + t;
        if (q < N) {
            float inv_r = 1.0f / radius[b];
            float na = naArr[t];
            if (role < 2) {
                float best = fminf(fminf(part[0][t][0],part[1][t][0]),
                                   fminf(part[2][t][0],part[3][t][0]));
                contrib = ((role==0)?0.8f:0.2f) * inv_r * (na + best);
            } else {
                float s0=FLT_INF,s1=FLT_INF,s2=FLT_INF,s3=FLT_INF,s4=FLT_INF;
                #pragma unroll
                for (int ww = 0; ww < NWAVE; ++ww)
                    #pragma unroll
                    for (int k = 0; k < 5; ++k)
                        INS5(s0,s1,s2,s3,s4, part[ww][t][k]);
                float ss[4] = {s1,s2,s3,s4};
                float s = 0.f;
                #pragma unroll
                for (int k = 0; k < 4; ++k) {
                    float d2 = fmaxf(na + ss[k], EPSV);
                    s += (RADIUS - sqrtf(d2)) * __expf(-d2 * INV_H2);
                }
                contrib = s;
            }
        }
    }
    #pragma unroll
    for (int off = 32; off > 0; off >>= 1) contrib += __shfl_down(contrib, off, 64);
    if (l == 0) red[w] = contrib;
    __syncthreads();
    if (threadIdx.x == 0)
        atomicAdd(&acc[role < 2 ? 0 : 1], red[0]+red[1]+red[2]+red[3]);
}

__global__ void upsample_final_kernel(const float* __restrict__ acc,
                                      float* __restrict__ out,
                                      float invCd, float invUni)
{
    out[0] = fmaf(acc[0], invCd, 0.1f * acc[1] * invUni);
}

extern "C" void kernel_launch(void* const* d_in, const int* in_sizes, int n_in,
                              void* d_out, int out_size, void* d_ws, size_t ws_size,
                              hipStream_t stream) {
    const float* pred   = (const float*)d_in[0];
    const float* gt     = (const float*)d_in[1];
    const float* radius = (const float*)d_in[2];
    float* out = (float*)d_out;
    float* acc = (float*)d_ws;

    int B = in_sizes[2];
    int N = in_sizes[0] / (3 * B);
    size_t BN = (size_t)B * N;

    hipMemsetAsync(acc, 0, 2 * sizeof(float), stream);

    size_t knnBytes = BN * KSPLIT * 5 * sizeof(float);
    size_t need = 64 + knnBytes;

    if (ws_size >= need) {
        float* knnPart = (float*)((char*)d_ws + 64);
        int chunks = (N + QB - 1) / QB;
        int knnItems  = B * chunks * KSPLIT;
        int chamItems = 2 * B * chunks;
        scan_kernel<<<knnItems + chamItems, THREADS, 0, stream>>>(
            pred, gt, radius, acc, knnPart, B, N, chunks, knnItems);
        int mb = (int)((BN + THREADS - 1) / THREADS);
        mergeB_kernel<<<mb, THREADS, 0, stream>>>(pred, knnPart, acc, B, N);
    } else {
        int chunksPerBatch = (N + 127) / 128;
        int blocks = 3 * B * chunksPerBatch;
        mono_kernel<<<blocks, THREADS, 0, stream>>>(pred, gt, radius, acc,
                                                    B, N, chunksPerBatch);
    }

    float invCd  = 1.0f / ((float)B * (float)N);
    float invUni = 1.0f / ((float)B * (float)N * 4.0f);
    upsample_final_kernel<<<1, 1, 0, stream>>>(acc, out, invCd, invUni);
}

// Round 8
// 72.927 us; speedup vs baseline: 1.9741x; 1.2964x over previous
//
#include <hip/hip_runtime.h>
#include <math.h>

#define THREADS 256
#define NWAVE 4
#define QB 128           // queries per block (2 per lane)
#define TILE 1024        // targets staged per LDS tile (16 KB)
#define KSPLIT 2         // knn target split factor

#define MED3 __builtin_amdgcn_fmed3f

// branchless sorted insert via med3: 5 independent ops, no serial chain.
#define INS5(L0,L1,L2,L3,L4,C) do { float c_=(C);              \
    float n0_=fminf(L0,c_);                                    \
    float n1_=MED3(L0,L1,c_);                                  \
    float n2_=MED3(L1,L2,c_);                                  \
    float n3_=MED3(L2,L3,c_);                                  \
    float n4_=MED3(L3,L4,c_);                                  \
    L0=n0_; L1=n1_; L2=n2_; L3=n3_; L4=n4_; } while (0)

// tile stores (-2x, -2y, -2z, |t|^2): dist-na = 3 fma
__device__ __forceinline__ float cdist(float qx,float qy,float qz,float4 t) {
    return fmaf(qx, t.x, fmaf(qy, t.y, fmaf(qz, t.z, t.w)));
}

// blocks [0, knnItems): role 2 (knn), targets split KSPLIT ways -> knnPart
// blocks [knnItems,...): roles 0/1 (chamfer), full scan -> atomic acc[0]
__global__ __launch_bounds__(THREADS) void scan_kernel(
    const float* __restrict__ pred, const float* __restrict__ gt,
    const float* __restrict__ radius, float* __restrict__ acc,
    float* __restrict__ knnPart, int B, int N, int chunks, int knnItems)
{
    __shared__ float4 tile[TILE];
    __shared__ float part[NWAVE][QB][5];
    __shared__ float red[NWAVE];

    const float FLT_INF = 3.4e38f;

    int w = threadIdx.x >> 6, l = threadIdx.x & 63;

    int role, b, chunk, split = 0, tBegin, tEnd;
    if ((int)blockIdx.x < knnItems) {
        role = 2;
        int u = blockIdx.x;
        split = u % KSPLIT; u /= KSPLIT;
        chunk = u % chunks; b = u / chunks;
        int seg = (N + KSPLIT - 1) / KSPLIT;
        tBegin = split * seg; tEnd = min(tBegin + seg, N);
    } else {
        int u = blockIdx.x - knnItems;
        int perRole = B * chunks;
        role = u / perRole; u %= perRole;
        chunk = u % chunks; b = u / chunks;
        tBegin = 0; tEnd = N;
    }

    int qi0 = chunk * QB + l;        // query for slot l
    int qi1 = qi0 + 64;              // query for slot l+64
    const float* qb = (((role == 0) ? gt : pred)) + (size_t)b * N * 3;
    const float* tb = (((role == 1) ? gt : pred)) + (size_t)b * N * 3;

    float ax = 0.f, ay = 0.f, az = 0.f, bx = 0.f, by = 0.f, bz = 0.f;
    if (qi0 < N) { ax = qb[qi0*3]; ay = qb[qi0*3+1]; az = qb[qi0*3+2]; }
    if (qi1 < N) { bx = qb[qi1*3]; by = qb[qi1*3+1]; bz = qb[qi1*3+2]; }

    // chamfer: 2 chains per query for ILP
    float mA0 = FLT_INF, mA1 = FLT_INF, mB0 = FLT_INF, mB1 = FLT_INF;
    // knn: top-5 lists per query
    float e0=FLT_INF,e1=FLT_INF,e2=FLT_INF,e3=FLT_INF,e4=FLT_INF;
    float o0=FLT_INF,o1=FLT_INF,o2=FLT_INF,o3=FLT_INF,o4=FLT_INF;

    for (int t0 = tBegin; t0 < tEnd; t0 += TILE) {
        int cnt = min(TILE, tEnd - t0);
        for (int k = threadIdx.x; k < cnt; k += THREADS) {
            float x = tb[(size_t)(t0 + k) * 3 + 0];
            float y = tb[(size_t)(t0 + k) * 3 + 1];
            float z = tb[(size_t)(t0 + k) * 3 + 2];
            float nb = fmaf(x, x, fmaf(y, y, z * z));
            tile[k] = make_float4(-2.f * x, -2.f * y, -2.f * z, nb);
        }
        __syncthreads();

        int seg = (cnt + NWAVE - 1) / NWAVE;
        int jb = w * seg, je = min(jb + seg, cnt);

        if (role < 2) {
            int j = jb;
            for (; j + 4 <= je; j += 4) {
                float4 t0v = tile[j], t1v = tile[j+1], t2v = tile[j+2], t3v = tile[j+3];
                mA0 = fminf(mA0, cdist(ax,ay,az,t0v));
                mB0 = fminf(mB0, cdist(bx,by,bz,t0v));
                mA1 = fminf(mA1, cdist(ax,ay,az,t1v));
                mB1 = fminf(mB1, cdist(bx,by,bz,t1v));
                mA0 = fminf(mA0, cdist(ax,ay,az,t2v));
                mB0 = fminf(mB0, cdist(bx,by,bz,t2v));
                mA1 = fminf(mA1, cdist(ax,ay,az,t3v));
                mB1 = fminf(mB1, cdist(bx,by,bz,t3v));
            }
            for (; j < je; ++j) {
                float4 t = tile[j];
                mA0 = fminf(mA0, cdist(ax,ay,az,t));
                mB0 = fminf(mB0, cdist(bx,by,bz,t));
            }
        } else {
            int j = jb;
            for (; j + 2 <= je; j += 2) {
                float4 t0v = tile[j], t1v = tile[j+1];
                float cA0 = cdist(ax,ay,az,t0v), cB0 = cdist(bx,by,bz,t0v);
                float cA1 = cdist(ax,ay,az,t1v), cB1 = cdist(bx,by,bz,t1v);
                INS5(e0,e1,e2,e3,e4, cA0);
                INS5(o0,o1,o2,o3,o4, cB0);
                INS5(e0,e1,e2,e3,e4, cA1);
                INS5(o0,o1,o2,o3,o4, cB1);
            }
            for (; j < je; ++j) {
                float4 t = tile[j];
                INS5(e0,e1,e2,e3,e4, cdist(ax,ay,az,t));
                INS5(o0,o1,o2,o3,o4, cdist(bx,by,bz,t));
            }
        }
        __syncthreads();
    }

    if (role < 2) {
        part[w][l][0]      = fminf(mA0, mA1);
        part[w][l + 64][0] = fminf(mB0, mB1);
    } else {
        part[w][l][0]=e0; part[w][l][1]=e1; part[w][l][2]=e2;
        part[w][l][3]=e3; part[w][l][4]=e4;
        part[w][l+64][0]=o0; part[w][l+64][1]=o1; part[w][l+64][2]=o2;
        part[w][l+64][3]=o3; part[w][l+64][4]=o4;
    }
    __syncthreads();

    if (role < 2) {
        float contrib = 0.f;
        if (threadIdx.x < QB) {
            int t = threadIdx.x;
            int q = chunk * QB + t;
            if (q < N) {
                float x = qb[q*3], y = qb[q*3+1], z = qb[q*3+2];
                float na = fmaf(x,x,fmaf(y,y,z*z));
                float best = fminf(fminf(part[0][t][0], part[1][t][0]),
                                   fminf(part[2][t][0], part[3][t][0]));
                float wgt = (role == 0) ? 0.8f : 0.2f;
                contrib = wgt * (na + best) / radius[b];
            }
        }
        #pragma unroll
        for (int off = 32; off > 0; off >>= 1) contrib += __shfl_down(contrib, off, 64);
        if (l == 0) red[w] = contrib;
        __syncthreads();
        if (threadIdx.x == 0) atomicAdd(&acc[0], red[0]+red[1]+red[2]+red[3]);
    } else {
        if (threadIdx.x < QB) {
            int t = threadIdx.x;
            int q = chunk * QB + t;
            if (q < N) {
                float s0=FLT_INF,s1=FLT_INF,s2=FLT_INF,s3=FLT_INF,s4=FLT_INF;
                #pragma unroll
                for (int ww = 0; ww < NWAVE; ++ww)
                    #pragma unroll
                    for (int k = 0; k < 5; ++k)
                        INS5(s0,s1,s2,s3,s4, part[ww][t][k]);
                float* kp = &knnPart[(((size_t)b * N + q) * KSPLIT + split) * 5];
                kp[0]=s0; kp[1]=s1; kp[2]=s2; kp[3]=s3; kp[4]=s4;
            }
        }
    }
}

// merge knn partials -> uniform loss into acc[1]
__global__ __launch_bounds__(THREADS) void mergeB_kernel(
    const float* __restrict__ pred, const float* __restrict__ knnPart,
    float* __restrict__ acc, int B, int N)
{
    const float FLT_INF = 3.4e38f;
    const float RADIUS = 0.07f;
    const float INV_H2 = 1.0f / (0.03f * 0.03f);
    const float EPSV = 1e-12f;

    __shared__ float redu[NWAVE];

    int gid = blockIdx.x * THREADS + threadIdx.x;
    int BN = B * N;
    float uni = 0.f;

    if (gid < BN) {
        const float* qp = pred + (size_t)gid * 3;
        float x = qp[0], y = qp[1], z = qp[2];
        float na = fmaf(x,x,fmaf(y,y,z*z));
        const float* kp = &knnPart[(size_t)gid * KSPLIT * 5];
        float s0=FLT_INF,s1=FLT_INF,s2=FLT_INF,s3=FLT_INF,s4=FLT_INF;
        #pragma unroll
        for (int k = 0; k < KSPLIT * 5; ++k) INS5(s0,s1,s2,s3,s4, kp[k]);
        // s0 == self (global min): dropped. ranks 1..4 = 4-NN.
        float ss[4] = {s1, s2, s3, s4};
        #pragma unroll
        for (int k = 0; k < 4; ++k) {
            float d2 = fmaxf(na + ss[k], EPSV);
            uni += (RADIUS - sqrtf(d2)) * __expf(-d2 * INV_H2);
        }
    }

    int w = threadIdx.x >> 6, l = threadIdx.x & 63;
    #pragma unroll
    for (int off = 32; off > 0; off >>= 1) uni += __shfl_down(uni, off, 64);
    if (l == 0) redu[w] = uni;
    __syncthreads();
    if (threadIdx.x == 0)
        atomicAdd(&acc[1], redu[0]+redu[1]+redu[2]+redu[3]);
}

// ---------------- Fallback: proven monolithic kernel (small ws) ----------------
__device__ __forceinline__ float sdist(float qx,float qy,float qz,float4 t) {
    return fmaf(-2.f, fmaf(qx,t.x,fmaf(qy,t.y,qz*t.z)), t.w);
}
__global__ __launch_bounds__(THREADS) void mono_kernel(
    const float* __restrict__ pred, const float* __restrict__ gt,
    const float* __restrict__ radius, float* __restrict__ acc,
    int B, int N, int chunksPerBatch)
{
    __shared__ float4 tgt[2048];
    __shared__ float part[NWAVE][128][5];
    __shared__ float naArr[128];
    __shared__ float red[NWAVE];
    const float FLT_INF = 3.4e38f;
    const float RADIUS = 0.07f;
    const float INV_H2 = 1.0f / (0.03f * 0.03f);
    const float EPSV = 1e-12f;

    int blocksPerRole = B * chunksPerBatch;
    int role  = blockIdx.x / blocksPerRole;
    int rem   = blockIdx.x % blocksPerRole;
    int b     = rem / chunksPerBatch;
    int chunk = rem % chunksPerBatch;
    int w = threadIdx.x >> 6, l = threadIdx.x & 63;
    int qi0 = chunk * 128 + l, qi1 = qi0 + 64;
    const float* qb = (((role == 0) ? gt : pred)) + (size_t)b * N * 3;
    const float* tb = (((role == 1) ? gt : pred)) + (size_t)b * N * 3;
    float q0x=0,q0y=0,q0z=0,q1x=0,q1y=0,q1z=0;
    if (qi0 < N) { q0x=qb[qi0*3]; q0y=qb[qi0*3+1]; q0z=qb[qi0*3+2]; }
    if (qi1 < N) { q1x=qb[qi1*3]; q1y=qb[qi1*3+1]; q1z=qb[qi1*3+2]; }
    float na0 = fmaf(q0x,q0x,fmaf(q0y,q0y,q0z*q0z));
    float na1 = fmaf(q1x,q1x,fmaf(q1y,q1y,q1z*q1z));
    if (w == 0) { naArr[l] = na0; naArr[l+64] = na1; }
    float mA=FLT_INF,mB=FLT_INF;
    float e0=FLT_INF,e1=FLT_INF,e2=FLT_INF,e3=FLT_INF,e4=FLT_INF;
    float o0=FLT_INF,o1=FLT_INF,o2=FLT_INF,o3=FLT_INF,o4=FLT_INF;
    for (int t0 = 0; t0 < N; t0 += 2048) {
        int cnt = min(2048, N - t0);
        for (int k = threadIdx.x; k < cnt; k += THREADS) {
            float x = tb[(size_t)(t0+k)*3], y = tb[(size_t)(t0+k)*3+1], z = tb[(size_t)(t0+k)*3+2];
            tgt[k] = make_float4(x,y,z,fmaf(x,x,fmaf(y,y,z*z)));
        }
        __syncthreads();
        int segsz = (cnt + NWAVE - 1)/NWAVE;
        int jb = w*segsz, je = min(jb+segsz, cnt);
        if (role < 2) {
            for (int j = jb; j < je; ++j) {
                float4 t = tgt[j];
                mA = fminf(mA, sdist(q0x,q0y,q0z,t));
                mB = fminf(mB, sdist(q1x,q1y,q1z,t));
            }
        } else {
            for (int j = jb; j < je; ++j) {
                float4 t = tgt[j];
                INS5(e0,e1,e2,e3,e4, sdist(q0x,q0y,q0z,t));
                INS5(o0,o1,o2,o3,o4, sdist(q1x,q1y,q1z,t));
            }
        }
        __syncthreads();
    }
    if (role < 2) { part[w][l][0]=mA; part[w][l+64][0]=mB; }
    else {
        part[w][l][0]=e0; part[w][l][1]=e1; part[w][l][2]=e2; part[w][l][3]=e3; part[w][l][4]=e4;
        part[w][l+64][0]=o0; part[w][l+64][1]=o1; part[w][l+64][2]=o2; part[w][l+64][3]=o3; part[w][l+64][4]=o4;
    }
    __syncthreads();
    float contrib = 0.f;
    int t = threadIdx.x;
    if (t < 128) {
        int q = chunk*128 + t;
        if (q < N) {
            float inv_r = 1.0f / radius[b];
            float na = naArr[t];
            if (role < 2) {
                float best = fminf(fminf(part[0][t][0],part[1][t][0]),
                                   fminf(part[2][t][0],part[3][t][0]));
                contrib = ((role==0)?0.8f:0.2f) * inv_r * (na + best);
            } else {
                float s0=FLT_INF,s1=FLT_INF,s2=FLT_INF,s3=FLT_INF,s4=FLT_INF;
                #pragma unroll
                for (int ww = 0; ww < NWAVE; ++ww)
                    #pragma unroll
                    for (int k = 0; k < 5; ++k)
                        INS5(s0,s1,s2,s3,s4, part[ww][t][k]);
                float ss[4] = {s1,s2,s3,s4};
                float s = 0.f;
                #pragma unroll
                for (int k = 0; k < 4; ++k) {
                    float d2 = fmaxf(na + ss[k], EPSV);
                    s += (RADIUS - sqrtf(d2)) * __expf(-d2 * INV_H2);
                }
                contrib = s;
            }
        }
    }
    #pragma unroll
    for (int off = 32; off > 0; off >>= 1) contrib += __shfl_down(contrib, off, 64);
    if (l == 0) red[w] = contrib;
    __syncthreads();
    if (threadIdx.x == 0)
        atomicAdd(&acc[role < 2 ? 0 : 1], red[0]+red[1]+red[2]+red[3]);
}

__global__ void upsample_final_kernel(const float* __restrict__ acc,
                                      float* __restrict__ out,
                                      float invCd, float invUni)
{
    out[0] = fmaf(acc[0], invCd, 0.1f * acc[1] * invUni);
}

extern "C" void kernel_launch(void* const* d_in, const int* in_sizes, int n_in,
                              void* d_out, int out_size, void* d_ws, size_t ws_size,
                              hipStream_t stream) {
    const float* pred   = (const float*)d_in[0];
    const float* gt     = (const float*)d_in[1];
    const float* radius = (const float*)d_in[2];
    float* out = (float*)d_out;
    float* acc = (float*)d_ws;

    int B = in_sizes[2];
    int N = in_sizes[0] / (3 * B);
    size_t BN = (size_t)B * N;

    hipMemsetAsync(acc, 0, 2 * sizeof(float), stream);

    size_t knnBytes = BN * KSPLIT * 5 * sizeof(float);
    size_t need = 64 + knnBytes;

    if (ws_size >= need) {
        float* knnPart = (float*)((char*)d_ws + 64);
        int chunks = (N + QB - 1) / QB;
        int knnItems  = B * chunks * KSPLIT;
        int chamItems = 2 * B * chunks;
        scan_kernel<<<knnItems + chamItems, THREADS, 0, stream>>>(
            pred, gt, radius, acc, knnPart, B, N, chunks, knnItems);
        int mb = (int)((BN + THREADS - 1) / THREADS);
        mergeB_kernel<<<mb, THREADS, 0, stream>>>(pred, knnPart, acc, B, N);
    } else {
        int chunksPerBatch = (N + 127) / 128;
        int blocks = 3 * B * chunksPerBatch;
        mono_kernel<<<blocks, THREADS, 0, stream>>>(pred, gt, radius, acc,
                                                    B, N, chunksPerBatch);
    }

    float invCd  = 1.0f / ((float)B * (float)N);
    float invUni = 1.0f / ((float)B * (float)N * 4.0f);
    upsample_final_kernel<<<1, 1, 0, stream>>>(acc, out, invCd, invUni);
}